// Round 1
// baseline (961.914 us; speedup 1.0000x reference)
//
#include <hip/hip_runtime.h>
#include <hip/hip_bf16.h>

#define N_LITS    131072
#define N_CLAUSES 65536
#define N_EDGES   524288
#define FEAT      384
#define F2        768
#define H1        256
#define H2        64

typedef __bf16 bf16_t;
typedef __attribute__((ext_vector_type(8))) __bf16 bf16x8;
typedef __attribute__((ext_vector_type(4))) __bf16 bf16x4;
typedef __attribute__((ext_vector_type(4))) float f32x4;

// ---- workspace layout (bytes) ----
#define OFF_W1T   0                         // bf16 [256][768]
#define OFF_W2T   (256 * 768 * 2)           // bf16 [64][256]
#define OFF_W3T   (OFF_W2T + 64 * 256 * 2)  // bf16 [32][64] (rows n>=20 zero)
#define OFF_SUMS  (OFF_W3T + 32 * 64 * 2)   // f32 [65536]
#define OFF_CNTS  (OFF_SUMS + 65536 * 4)    // f32 [65536]
#define OFF_LB    (OFF_CNTS + 65536 * 4)    // bf16 [131072][384]  (16B aligned)
#define OFF_CB    (OFF_LB + (size_t)N_LITS * FEAT * 2)  // bf16 [65536][384]
#define WS_NEED   (OFF_CB + (size_t)N_CLAUSES * FEAT * 2)

// LDS strides (elements)
#define ASTR 104   // Abuf row stride: 96 + 8 pad  (2-way banks max)
#define H1STR 264  // h1 row stride: 256 + 8 pad
#define H2STR 72   // h2 row stride: 64 + 8 pad

// Fused transpose+cast of W1, W2, W3 (padded to 32 cols).
__global__ void k_prep(const float* __restrict__ W1, const float* __restrict__ W2,
                       const float* __restrict__ W3, bf16_t* __restrict__ W1T,
                       bf16_t* __restrict__ W2T, bf16_t* __restrict__ W3T) {
  int idx = blockIdx.x * blockDim.x + threadIdx.x;
  if (idx < 196608) {
    int n = idx / 768, k = idx - n * 768;
    W1T[idx] = (bf16_t)W1[k * 256 + n];
  } else if (idx < 196608 + 16384) {
    int i = idx - 196608;
    int n = i / 256, k = i - n * 256;
    W2T[i] = (bf16_t)W2[k * 64 + n];
  } else if (idx < 196608 + 16384 + 2048) {
    int i = idx - 196608 - 16384;
    int n = i / 64, k = i - n * 64;
    W3T[i] = (bf16_t)((n < 20) ? W3[k * 20 + n] : 0.0f);
  }
}

// Grid-stride f32 -> bf16 cast, 8 elements/thread (2x float4 load, 1x 16B store).
__global__ void k_cast_emb(const float* __restrict__ src, bf16_t* __restrict__ dst,
                           int n8) {
  int i = blockIdx.x * blockDim.x + threadIdx.x;
  int stride = gridDim.x * blockDim.x;
  for (; i < n8; i += stride) {
    float4 a = ((const float4*)src)[2 * i];
    float4 b = ((const float4*)src)[2 * i + 1];
    bf16x8 o;
    o[0] = (bf16_t)a.x; o[1] = (bf16_t)a.y; o[2] = (bf16_t)a.z; o[3] = (bf16_t)a.w;
    o[4] = (bf16_t)b.x; o[5] = (bf16_t)b.y; o[6] = (bf16_t)b.z; o[7] = (bf16_t)b.w;
    *(bf16x8*)(dst + (size_t)i * 8) = o;
  }
}

template <int USE_BF16>
__global__ __launch_bounds__(256, 3) void k_edge_mlp(
    const float* __restrict__ l_embs, const float* __restrict__ c_embs,
    const bf16_t* __restrict__ lb, const bf16_t* __restrict__ cb,
    const int* __restrict__ edge_i, const int* __restrict__ edge_j,
    const bf16_t* __restrict__ W1T, const bf16_t* __restrict__ W2T,
    const bf16_t* __restrict__ W3T,
    const float* __restrict__ b1, const float* __restrict__ b2,
    const float* __restrict__ b3, const float* __restrict__ W4,
    const float* __restrict__ b4,
    float* __restrict__ sums, float* __restrict__ counts)
{
  // Abuf [64][ASTR] unioned with h2 [64][H2STR]; h1 [64][H1STR] separate.
  __shared__ __align__(16) char smem[64 * ASTR * 2 + 64 * H1STR * 2];
  bf16_t* Abuf = (bf16_t*)smem;                    // layer-1 A staging
  bf16_t* h2s  = (bf16_t*)smem;                    // reused after layer 1
  bf16_t* h1   = (bf16_t*)(smem + 64 * ASTR * 2);

  const int t    = threadIdx.x;
  const int wave = t >> 6;
  const int lane = t & 63;
  const int m    = lane & 15;
  const int quad = lane >> 4;
  const int e0   = blockIdx.x * 64;
  const int wn   = wave * 64;      // this wave's N-base in layer 1

  // ---- staging identity: thread t owns row r=t/4, col-phase sub=t%4 ----
  // chunk cc covers global k in [cc*96, cc*96+96).
  // f32 path:  6x float4 at cols sub*4 + q*16.
  // bf16 path: 3x bf16x8 at cols sub*8 + q*32.
  const int sr  = t >> 2;
  const int sub = t & 3;
  const int ri  = edge_i[e0 + sr];
  const int rj  = edge_j[e0 + sr];

  const float*  pLf = l_embs + (size_t)ri * FEAT + sub * 4;
  const float*  pCf = c_embs + (size_t)rj * FEAT + sub * 4;
  const bf16_t* pLb = lb + (size_t)ri * FEAT + sub * 8;
  const bf16_t* pCb = cb + (size_t)rj * FEAT + sub * 8;
  bf16_t* sdst = Abuf + sr * ASTR + (USE_BF16 ? sub * 8 : sub * 4);

  f32x4 acc[4][4];
#pragma unroll
  for (int mt = 0; mt < 4; ++mt)
#pragma unroll
    for (int nt = 0; nt < 4; ++nt) acc[mt][nt] = (f32x4){0.f, 0.f, 0.f, 0.f};

  const bf16_t* wb1 = W1T + (size_t)(wn + m) * F2 + quad * 8;

  // ---- prologue: stage chunk 0 ----
  if constexpr (USE_BF16) {
#pragma unroll
    for (int q = 0; q < 3; ++q)
      *(bf16x8*)(sdst + q * 32) = *(const bf16x8*)(pLb + q * 32);
  } else {
    const float* p = pLf;  // chunk 0 < 384
    float4 v[6];
#pragma unroll
    for (int q = 0; q < 6; ++q) v[q] = *(const float4*)(p + q * 16);
#pragma unroll
    for (int q = 0; q < 6; ++q) {
      bf16x4 c;
      c[0] = (bf16_t)v[q].x; c[1] = (bf16_t)v[q].y;
      c[2] = (bf16_t)v[q].z; c[3] = (bf16_t)v[q].w;
      *(bf16x4*)(sdst + q * 16) = c;
    }
  }

  // ---- layer 1: C1[64,256] = emb[64,768] @ W1, K-chunks of 96 ----
  for (int cc = 0; cc < 8; ++cc) {
    // prefetch next chunk into registers (latency hides under MFMA)
    float4 vn[6];
    bf16x8 vnB[3];
    if (cc < 7) {
      if constexpr (USE_BF16) {
        const bf16_t* p = (cc + 1 < 4) ? (pLb + (cc + 1) * 96) : (pCb + (cc + 1 - 4) * 96);
#pragma unroll
        for (int q = 0; q < 3; ++q) vnB[q] = *(const bf16x8*)(p + q * 32);
      } else {
        const float* p = (cc + 1 < 4) ? (pLf + (cc + 1) * 96) : (pCf + (cc + 1 - 4) * 96);
#pragma unroll
        for (int q = 0; q < 6; ++q) vn[q] = *(const float4*)(p + q * 16);
      }
    }
    __syncthreads();   // chunk cc's LDS writes visible
#pragma unroll
    for (int s = 0; s < 3; ++s) {
      bf16x8 af[4];
#pragma unroll
      for (int mt = 0; mt < 4; ++mt)
        af[mt] = *(const bf16x8*)(Abuf + (mt * 16 + m) * ASTR + s * 32 + quad * 8);
      const bf16_t* wb = wb1 + cc * 96 + s * 32;
#pragma unroll
      for (int nt = 0; nt < 4; ++nt) {
        bf16x8 b = *(const bf16x8*)(wb + (size_t)nt * 16 * F2);
#pragma unroll
        for (int mt = 0; mt < 4; ++mt)
          acc[mt][nt] = __builtin_amdgcn_mfma_f32_16x16x32_bf16(af[mt], b, acc[mt][nt], 0, 0, 0);
      }
    }
    if (cc < 7) {
      __syncthreads();  // all waves done reading chunk cc
      if constexpr (USE_BF16) {
#pragma unroll
        for (int q = 0; q < 3; ++q) *(bf16x8*)(sdst + q * 32) = vnB[q];
      } else {
#pragma unroll
        for (int q = 0; q < 6; ++q) {
          bf16x4 c;
          c[0] = (bf16_t)vn[q].x; c[1] = (bf16_t)vn[q].y;
          c[2] = (bf16_t)vn[q].z; c[3] = (bf16_t)vn[q].w;
          *(bf16x4*)(sdst + q * 16) = c;
        }
      }
    }
  }

  // ---- bias + relu + cvt -> h1 (A-layout for layer 2) ----
#pragma unroll
  for (int nt = 0; nt < 4; ++nt) {
    int col = wn + nt * 16 + m;
    float bb = b1[col];
#pragma unroll
    for (int mt = 0; mt < 4; ++mt)
#pragma unroll
      for (int r = 0; r < 4; ++r)
        h1[(mt * 16 + quad * 4 + r) * H1STR + col] =
            (bf16_t)fmaxf(acc[mt][nt][r] + bb, 0.0f);
  }
  __syncthreads();

  // ---- layer 2: each wave takes 16 edges (rows er..er+15) ----
  const int er = wave * 16;
  f32x4 acc2[4];
#pragma unroll
  for (int nt = 0; nt < 4; ++nt) acc2[nt] = (f32x4){0.f, 0.f, 0.f, 0.f};
#pragma unroll
  for (int s2 = 0; s2 < 8; ++s2) {
    bf16x8 a2 = *(const bf16x8*)(h1 + (er + m) * H1STR + s2 * 32 + quad * 8);
#pragma unroll
    for (int nt = 0; nt < 4; ++nt) {
      bf16x8 b = *(const bf16x8*)(W2T + (size_t)(nt * 16 + m) * H1 + s2 * 32 + quad * 8);
      acc2[nt] = __builtin_amdgcn_mfma_f32_16x16x32_bf16(a2, b, acc2[nt], 0, 0, 0);
    }
  }
  // h2s overlaps Abuf: safe, all Abuf reads completed before the sync above.
#pragma unroll
  for (int nt = 0; nt < 4; ++nt) {
    float bb = b2[nt * 16 + m];
#pragma unroll
    for (int r = 0; r < 4; ++r)
      h2s[(er + quad * 4 + r) * H2STR + nt * 16 + m] =
          (bf16_t)fmaxf(acc2[nt][r] + bb, 0.0f);
  }
  // rows er..er+15 are written and read only by this wave: no barrier needed.

  // ---- layer 3: C3[16,32] = h2[16,64] @ W3pad ----
  f32x4 acc3[2];
#pragma unroll
  for (int nt = 0; nt < 2; ++nt) acc3[nt] = (f32x4){0.f, 0.f, 0.f, 0.f};
#pragma unroll
  for (int s3 = 0; s3 < 2; ++s3) {
    bf16x8 a3 = *(const bf16x8*)(h2s + (er + m) * H2STR + s3 * 32 + quad * 8);
#pragma unroll
    for (int nt = 0; nt < 2; ++nt) {
      bf16x8 b = *(const bf16x8*)(W3T + (size_t)(nt * 16 + m) * H2 + s3 * 32 + quad * 8);
      acc3[nt] = __builtin_amdgcn_mfma_f32_16x16x32_bf16(a3, b, acc3[nt], 0, 0, 0);
    }
  }

  // ---- layer 4 + per-clause atomics ----
  float b3A = b3[m];
  float b3B = (m + 16 < 20) ? b3[m + 16] : 0.0f;
  float w4A = W4[m];
  float w4B = (m + 16 < 20) ? W4[m + 16] : 0.0f;

  float p[4];
#pragma unroll
  for (int r = 0; r < 4; ++r) {
    float hA = fmaxf(acc3[0][r] + b3A, 0.0f);
    float hB = fmaxf(acc3[1][r] + b3B, 0.0f);
    p[r] = hA * w4A + hB * w4B;
  }
#pragma unroll
  for (int d = 1; d < 16; d <<= 1) {
#pragma unroll
    for (int r = 0; r < 4; ++r) p[r] += __shfl_xor(p[r], d, 64);
  }

  if (m == 0) {
    float bb4 = b4[0];
#pragma unroll
    for (int r = 0; r < 4; ++r) {
      int row = er + quad * 4 + r;
      int ej = edge_j[e0 + row];
      atomicAdd(&sums[ej], p[r] + bb4);
      atomicAdd(&counts[ej], 1.0f);
    }
  }
}

// out[e] = sums[edge_j[e]] / max(counts[edge_j[e]], 1)  (mean fused into gather)
__global__ void k_gather(const float* __restrict__ sums, const float* __restrict__ counts,
                         const int* __restrict__ edge_j, float* __restrict__ out) {
  int e = blockIdx.x * blockDim.x + threadIdx.x;
  if (e >= N_EDGES) return;
  int ej = edge_j[e];
  out[e] = sums[ej] / fmaxf(counts[ej], 1.0f);
}

extern "C" void kernel_launch(void* const* d_in, const int* in_sizes, int n_in,
                              void* d_out, int out_size, void* d_ws, size_t ws_size,
                              hipStream_t stream) {
  const float* l_embs = (const float*)d_in[0];
  const float* c_embs = (const float*)d_in[1];
  const int*   edge_i = (const int*)d_in[2];
  const int*   edge_j = (const int*)d_in[3];
  const float* W1 = (const float*)d_in[4];
  const float* b1 = (const float*)d_in[5];
  const float* W2 = (const float*)d_in[6];
  const float* b2 = (const float*)d_in[7];
  const float* W3 = (const float*)d_in[8];
  const float* b3 = (const float*)d_in[9];
  const float* W4 = (const float*)d_in[10];
  const float* b4 = (const float*)d_in[11];
  float* out = (float*)d_out;

  char* ws = (char*)d_ws;
  bf16_t* W1T = (bf16_t*)(ws + OFF_W1T);
  bf16_t* W2T = (bf16_t*)(ws + OFF_W2T);
  bf16_t* W3T = (bf16_t*)(ws + OFF_W3T);
  float*  sums   = (float*)(ws + OFF_SUMS);
  float*  counts = (float*)(ws + OFF_CNTS);
  bf16_t* lb = (bf16_t*)(ws + OFF_LB);
  bf16_t* cb = (bf16_t*)(ws + OFF_CB);

  const bool use_bf16 = ws_size >= WS_NEED;

  hipMemsetAsync(ws + OFF_SUMS, 0, 2 * N_CLAUSES * 4, stream);

  k_prep<<<840, 256, 0, stream>>>(W1, W2, W3, W1T, W2T, W3T);

  if (use_bf16) {
    // cast embedding tables to bf16 (151 MB total -> L3-resident for the gather)
    k_cast_emb<<<2048, 256, 0, stream>>>(l_embs, lb, N_LITS * FEAT / 8);
    k_cast_emb<<<2048, 256, 0, stream>>>(c_embs, cb, N_CLAUSES * FEAT / 8);
    k_edge_mlp<1><<<N_EDGES / 64, 256, 0, stream>>>(
        l_embs, c_embs, lb, cb, edge_i, edge_j, W1T, W2T, W3T,
        b1, b2, b3, W4, b4, sums, counts);
  } else {
    k_edge_mlp<0><<<N_EDGES / 64, 256, 0, stream>>>(
        l_embs, c_embs, (const bf16_t*)nullptr, (const bf16_t*)nullptr,
        edge_i, edge_j, W1T, W2T, W3T,
        b1, b2, b3, W4, b4, sums, counts);
  }

  k_gather<<<N_EDGES / 256, 256, 0, stream>>>(sums, counts, edge_j, out);
}

// Round 2
// 692.149 us; speedup vs baseline: 1.3897x; 1.3897x over previous
//
#include <hip/hip_runtime.h>
#include <hip/hip_bf16.h>

#define N_LITS    131072
#define N_CLAUSES 65536
#define N_EDGES   524288
#define FEAT      384
#define F2        768
#define H1        256
#define H2        64

typedef __bf16 bf16_t;
typedef __attribute__((ext_vector_type(8))) __bf16 bf16x8;
typedef __attribute__((ext_vector_type(4))) __bf16 bf16x4;
typedef __attribute__((ext_vector_type(4))) float f32x4;

// ---- workspace layout (bytes) ----
#define OFF_W1T   0                          // bf16 [256][768] (n-major, transposed)
#define OFF_W2T   (256 * 768 * 2)            // bf16 [64][256]
#define OFF_W3T   (OFF_W2T + 64 * 256 * 2)   // bf16 [32][64] (rows n>=20 zero)
#define OFF_SUMS  (OFF_W3T + 32 * 64 * 2)    // f32 [65536]
#define OFF_CNTS  (OFF_SUMS + 65536 * 4)     // f32 [65536]
#define OFF_X     (OFF_CNTS + 65536 * 4)     // XL then XC
// f32 tables: XL f32[131072][256], XC f32[65536][256]
#define XL_F32_BYTES ((size_t)N_LITS * H1 * 4)
#define XC_F32_BYTES ((size_t)N_CLAUSES * H1 * 4)
#define WS_F32    (OFF_X + XL_F32_BYTES + XC_F32_BYTES)
// bf16 tables fallback
#define XL_B16_BYTES ((size_t)N_LITS * H1 * 2)
#define XC_B16_BYTES ((size_t)N_CLAUSES * H1 * 2)
#define WS_B16    (OFF_X + XL_B16_BYTES + XC_B16_BYTES)

// LDS strides (elements)
#define ASTR 104   // Abuf row stride: 96 + 8 pad
#define H2STR 72   // h2 row stride: 64 + 8 pad

// Fused transpose+cast of W1, W2, W3 (padded to 32 cols).
__global__ void k_prep(const float* __restrict__ W1, const float* __restrict__ W2,
                       const float* __restrict__ W3, bf16_t* __restrict__ W1T,
                       bf16_t* __restrict__ W2T, bf16_t* __restrict__ W3T) {
  int idx = blockIdx.x * blockDim.x + threadIdx.x;
  if (idx < 196608) {
    int n = idx / 768, k = idx - n * 768;
    W1T[idx] = (bf16_t)W1[k * 256 + n];
  } else if (idx < 196608 + 16384) {
    int i = idx - 196608;
    int n = i / 256, k = i - n * 256;
    W2T[i] = (bf16_t)W2[k * 64 + n];
  } else if (idx < 196608 + 16384 + 2048) {
    int i = idx - 196608 - 16384;
    int n = i / 64, k = i - n * 64;
    W3T[i] = (bf16_t)((n < 20) ? W3[k * 20 + n] : 0.0f);
  }
}

// ---- precompute: XL = l_embs @ W1_top ; XC = c_embs @ W1_bot + b1 ----
// blocks [0, N_LITS/64) -> XL rows; [N_LITS/64, +N_CLAUSES/64) -> XC rows.
// 64 rows/block, 4 waves x 64 cols, K=384 in 4 chunks of 96.
template <int F32OUT>
__global__ __launch_bounds__(256, 3) void k_pre(
    const float* __restrict__ l_embs, const float* __restrict__ c_embs,
    const bf16_t* __restrict__ W1T, const float* __restrict__ b1,
    float* __restrict__ XLf, float* __restrict__ XCf,
    bf16_t* __restrict__ XLb, bf16_t* __restrict__ XCb)
{
  __shared__ __align__(16) bf16_t Abuf[64 * ASTR];

  const int t    = threadIdx.x;
  const int wave = t >> 6;
  const int lane = t & 63;
  const int m    = lane & 15;
  const int quad = lane >> 4;
  const int bid  = blockIdx.x;
  const bool isC = bid >= (N_LITS / 64);
  const int r0   = (isC ? bid - N_LITS / 64 : bid) * 64;
  const float* A = isC ? c_embs : l_embs;
  const int koff = isC ? FEAT : 0;   // which half of W1T's K range
  const int wn   = wave * 64;

  const int sr  = t >> 2;
  const int sub = t & 3;
  const float* pA = A + (size_t)(r0 + sr) * FEAT + sub * 4;
  bf16_t* sdst = Abuf + sr * ASTR + sub * 4;

  f32x4 acc[4][4];
#pragma unroll
  for (int mt = 0; mt < 4; ++mt)
#pragma unroll
    for (int nt = 0; nt < 4; ++nt) acc[mt][nt] = (f32x4){0.f, 0.f, 0.f, 0.f};

  const bf16_t* wb1 = W1T + (size_t)(wn + m) * F2 + koff + quad * 8;

  // prologue: stage chunk 0
  {
    float4 v[6];
#pragma unroll
    for (int q = 0; q < 6; ++q) v[q] = *(const float4*)(pA + q * 16);
#pragma unroll
    for (int q = 0; q < 6; ++q) {
      bf16x4 c;
      c[0] = (bf16_t)v[q].x; c[1] = (bf16_t)v[q].y;
      c[2] = (bf16_t)v[q].z; c[3] = (bf16_t)v[q].w;
      *(bf16x4*)(sdst + q * 16) = c;
    }
  }

  for (int cc = 0; cc < 4; ++cc) {
    float4 vn[6];
    if (cc < 3) {
#pragma unroll
      for (int q = 0; q < 6; ++q) vn[q] = *(const float4*)(pA + (cc + 1) * 96 + q * 16);
    }
    __syncthreads();
#pragma unroll
    for (int s = 0; s < 3; ++s) {
      bf16x8 af[4];
#pragma unroll
      for (int mt = 0; mt < 4; ++mt)
        af[mt] = *(const bf16x8*)(Abuf + (mt * 16 + m) * ASTR + s * 32 + quad * 8);
      const bf16_t* wb = wb1 + cc * 96 + s * 32;
#pragma unroll
      for (int nt = 0; nt < 4; ++nt) {
        bf16x8 b = *(const bf16x8*)(wb + (size_t)nt * 16 * F2);
#pragma unroll
        for (int mt = 0; mt < 4; ++mt)
          acc[mt][nt] = __builtin_amdgcn_mfma_f32_16x16x32_bf16(af[mt], b, acc[mt][nt], 0, 0, 0);
      }
    }
    if (cc < 3) {
      __syncthreads();
#pragma unroll
      for (int q = 0; q < 6; ++q) {
        bf16x4 c;
        c[0] = (bf16_t)vn[q].x; c[1] = (bf16_t)vn[q].y;
        c[2] = (bf16_t)vn[q].z; c[3] = (bf16_t)vn[q].w;
        *(bf16x4*)(sdst + q * 16) = c;
      }
    }
  }

  // epilogue: direct store (no relu; b1 folded into XC)
#pragma unroll
  for (int nt = 0; nt < 4; ++nt) {
    int col = wn + nt * 16 + m;
    float badd = isC ? b1[col] : 0.0f;
#pragma unroll
    for (int mt = 0; mt < 4; ++mt)
#pragma unroll
      for (int r = 0; r < 4; ++r) {
        size_t row = r0 + mt * 16 + quad * 4 + r;
        float v = acc[mt][nt][r] + badd;
        if constexpr (F32OUT) {
          (isC ? XCf : XLf)[row * H1 + col] = v;
        } else {
          (isC ? XCb : XLb)[row * H1 + col] = (bf16_t)v;
        }
      }
  }
}

// ---- per-edge: h1 = relu(XL[i] + XC[j]) in-register, layers 2-4, atomics ----
// 64 edges/block, 4 waves x 16 edges, no barriers.
template <int F32T>
__global__ __launch_bounds__(256, 4) void k_edge2(
    const float* __restrict__ XLf, const float* __restrict__ XCf,
    const bf16_t* __restrict__ XLb, const bf16_t* __restrict__ XCb,
    const int* __restrict__ edge_i, const int* __restrict__ edge_j,
    const bf16_t* __restrict__ W2T, const bf16_t* __restrict__ W3T,
    const float* __restrict__ b2, const float* __restrict__ b3,
    const float* __restrict__ W4, const float* __restrict__ b4,
    float* __restrict__ sums, float* __restrict__ counts)
{
  __shared__ __align__(16) bf16_t h2s[64 * H2STR];

  const int t    = threadIdx.x;
  const int wave = t >> 6;
  const int lane = t & 63;
  const int m    = lane & 15;
  const int quad = lane >> 4;
  const int e0   = blockIdx.x * 64;
  const int er   = wave * 16;

  // this lane's A-fragment row = edge er+m
  const int e  = e0 + er + m;
  const int ri = edge_i[e];
  const int rj = edge_j[e];
  const size_t baseL = (size_t)ri * H1;
  const size_t baseC = (size_t)rj * H1;

  f32x4 acc2[4];
#pragma unroll
  for (int nt = 0; nt < 4; ++nt) acc2[nt] = (f32x4){0.f, 0.f, 0.f, 0.f};

  // layer 2: K=256 in 8 steps of 32; A built in-register from gathered rows
#pragma unroll
  for (int g = 0; g < 2; ++g) {
    bf16x8 a2[4];
#pragma unroll
    for (int u = 0; u < 4; ++u) {
      const int s2 = g * 4 + u;
      const int off = s2 * 32 + quad * 8;
      bf16x8 a;
      if constexpr (F32T) {
        float4 xa = *(const float4*)(XLf + baseL + off);
        float4 xb = *(const float4*)(XLf + baseL + off + 4);
        float4 ya = *(const float4*)(XCf + baseC + off);
        float4 yb = *(const float4*)(XCf + baseC + off + 4);
        a[0] = (bf16_t)fmaxf(xa.x + ya.x, 0.f);
        a[1] = (bf16_t)fmaxf(xa.y + ya.y, 0.f);
        a[2] = (bf16_t)fmaxf(xa.z + ya.z, 0.f);
        a[3] = (bf16_t)fmaxf(xa.w + ya.w, 0.f);
        a[4] = (bf16_t)fmaxf(xb.x + yb.x, 0.f);
        a[5] = (bf16_t)fmaxf(xb.y + yb.y, 0.f);
        a[6] = (bf16_t)fmaxf(xb.z + yb.z, 0.f);
        a[7] = (bf16_t)fmaxf(xb.w + yb.w, 0.f);
      } else {
        bf16x8 xa = *(const bf16x8*)(XLb + baseL + off);
        bf16x8 ya = *(const bf16x8*)(XCb + baseC + off);
#pragma unroll
        for (int jj = 0; jj < 8; ++jj)
          a[jj] = (bf16_t)fmaxf((float)xa[jj] + (float)ya[jj], 0.f);
      }
      a2[u] = a;
    }
#pragma unroll
    for (int u = 0; u < 4; ++u) {
      const int s2 = g * 4 + u;
#pragma unroll
      for (int nt = 0; nt < 4; ++nt) {
        bf16x8 b = *(const bf16x8*)(W2T + (size_t)(nt * 16 + m) * H1 + s2 * 32 + quad * 8);
        acc2[nt] = __builtin_amdgcn_mfma_f32_16x16x32_bf16(a2[u], b, acc2[nt], 0, 0, 0);
      }
    }
  }

  // h2 -> LDS (rows er..er+15 owned by this wave; no barrier needed)
#pragma unroll
  for (int nt = 0; nt < 4; ++nt) {
    float bb = b2[nt * 16 + m];
#pragma unroll
    for (int r = 0; r < 4; ++r)
      h2s[(er + quad * 4 + r) * H2STR + nt * 16 + m] =
          (bf16_t)fmaxf(acc2[nt][r] + bb, 0.0f);
  }

  // layer 3: C3[16,32] = h2[16,64] @ W3pad
  f32x4 acc3[2];
#pragma unroll
  for (int nt = 0; nt < 2; ++nt) acc3[nt] = (f32x4){0.f, 0.f, 0.f, 0.f};
#pragma unroll
  for (int s3 = 0; s3 < 2; ++s3) {
    bf16x8 a3 = *(const bf16x8*)(h2s + (er + m) * H2STR + s3 * 32 + quad * 8);
#pragma unroll
    for (int nt = 0; nt < 2; ++nt) {
      bf16x8 b = *(const bf16x8*)(W3T + (size_t)(nt * 16 + m) * H2 + s3 * 32 + quad * 8);
      acc3[nt] = __builtin_amdgcn_mfma_f32_16x16x32_bf16(a3, b, acc3[nt], 0, 0, 0);
    }
  }

  // layer 4 + per-clause atomics
  float b3A = b3[m];
  float b3B = (m + 16 < 20) ? b3[m + 16] : 0.0f;
  float w4A = W4[m];
  float w4B = (m + 16 < 20) ? W4[m + 16] : 0.0f;

  float p[4];
#pragma unroll
  for (int r = 0; r < 4; ++r) {
    float hA = fmaxf(acc3[0][r] + b3A, 0.0f);
    float hB = fmaxf(acc3[1][r] + b3B, 0.0f);
    p[r] = hA * w4A + hB * w4B;
  }
#pragma unroll
  for (int d = 1; d < 16; d <<= 1) {
#pragma unroll
    for (int r = 0; r < 4; ++r) p[r] += __shfl_xor(p[r], d, 64);
  }

  if (m == 0) {
    float bb4 = b4[0];
#pragma unroll
    for (int r = 0; r < 4; ++r) {
      int row = er + quad * 4 + r;
      int ej = edge_j[e0 + row];
      atomicAdd(&sums[ej], p[r] + bb4);
      atomicAdd(&counts[ej], 1.0f);
    }
  }
}

// out[e] = sums[edge_j[e]] / max(counts[edge_j[e]], 1)
__global__ void k_gather(const float* __restrict__ sums, const float* __restrict__ counts,
                         const int* __restrict__ edge_j, float* __restrict__ out) {
  int e = blockIdx.x * blockDim.x + threadIdx.x;
  if (e >= N_EDGES) return;
  int ej = edge_j[e];
  out[e] = sums[ej] / fmaxf(counts[ej], 1.0f);
}

extern "C" void kernel_launch(void* const* d_in, const int* in_sizes, int n_in,
                              void* d_out, int out_size, void* d_ws, size_t ws_size,
                              hipStream_t stream) {
  const float* l_embs = (const float*)d_in[0];
  const float* c_embs = (const float*)d_in[1];
  const int*   edge_i = (const int*)d_in[2];
  const int*   edge_j = (const int*)d_in[3];
  const float* W1 = (const float*)d_in[4];
  const float* b1 = (const float*)d_in[5];
  const float* W2 = (const float*)d_in[6];
  const float* b2 = (const float*)d_in[7];
  const float* W3 = (const float*)d_in[8];
  const float* b3 = (const float*)d_in[9];
  const float* W4 = (const float*)d_in[10];
  const float* b4 = (const float*)d_in[11];
  float* out = (float*)d_out;

  char* ws = (char*)d_ws;
  bf16_t* W1T = (bf16_t*)(ws + OFF_W1T);
  bf16_t* W2T = (bf16_t*)(ws + OFF_W2T);
  bf16_t* W3T = (bf16_t*)(ws + OFF_W3T);
  float*  sums   = (float*)(ws + OFF_SUMS);
  float*  counts = (float*)(ws + OFF_CNTS);

  hipMemsetAsync(ws + OFF_SUMS, 0, 2 * N_CLAUSES * 4, stream);

  k_prep<<<840, 256, 0, stream>>>(W1, W2, W3, W1T, W2T, W3T);

  const int pre_grid = N_LITS / 64 + N_CLAUSES / 64;  // 3072

  if (ws_size >= WS_F32) {
    float* XLf = (float*)(ws + OFF_X);
    float* XCf = (float*)(ws + OFF_X + XL_F32_BYTES);
    k_pre<1><<<pre_grid, 256, 0, stream>>>(l_embs, c_embs, W1T, b1,
                                           XLf, XCf, nullptr, nullptr);
    k_edge2<1><<<N_EDGES / 64, 256, 0, stream>>>(
        XLf, XCf, nullptr, nullptr, edge_i, edge_j, W2T, W3T,
        b2, b3, W4, b4, sums, counts);
  } else {
    bf16_t* XLb = (bf16_t*)(ws + OFF_X);
    bf16_t* XCb = (bf16_t*)(ws + OFF_X + XL_B16_BYTES);
    k_pre<0><<<pre_grid, 256, 0, stream>>>(l_embs, c_embs, W1T, b1,
                                           nullptr, nullptr, XLb, XCb);
    k_edge2<0><<<N_EDGES / 64, 256, 0, stream>>>(
        nullptr, nullptr, XLb, XCb, edge_i, edge_j, W2T, W3T,
        b2, b3, W4, b4, sums, counts);
  }

  k_gather<<<N_EDGES / 256, 256, 0, stream>>>(sums, counts, edge_j, out);
}

// Round 5
// 609.308 us; speedup vs baseline: 1.5787x; 1.1360x over previous
//
#include <hip/hip_runtime.h>
#include <hip/hip_bf16.h>

#define N_LITS    131072
#define N_CLAUSES 65536
#define N_EDGES   524288
#define FEAT      384
#define F2        768
#define H1        256
#define H2        64

typedef __bf16 bf16_t;
typedef __attribute__((ext_vector_type(8))) __bf16 bf16x8;
typedef __attribute__((ext_vector_type(4))) __bf16 bf16x4;
typedef __attribute__((ext_vector_type(4))) float f32x4;

// ---- workspace layout (bytes) ----
#define OFF_W1T   0                          // bf16 [256][768] (n-major, transposed)
#define OFF_W2T   (256 * 768 * 2)            // bf16 [64][256]
#define OFF_W3T   (OFF_W2T + 64 * 256 * 2)   // bf16 [32][64] (rows n>=20 zero)
#define OFF_SC    (OFF_W3T + 32 * 64 * 2)    // f32 [65536][2] interleaved {sum,count}
#define OFF_X     (OFF_SC + 65536 * 8)       // XL bf16[131072][256], XC bf16[65536][256]
#define XL_BYTES  ((size_t)N_LITS * H1 * 2)
#define XC_BYTES  ((size_t)N_CLAUSES * H1 * 2)

// LDS strides (elements)
#define ASTR  104  // Abuf row stride: 96 + 8 pad
#define XSTR  264  // k_pre epilogue row stride: 256 + 8 pad
#define H2STR 72   // h2 row stride: 64 + 8 pad

// Fused: transpose+cast W1,W2,W3 AND zero the sum/count table.
// weights: idx < 215040; zeroing: 32768 float4 threads.
__global__ void k_prep(const float* __restrict__ W1, const float* __restrict__ W2,
                       const float* __restrict__ W3, bf16_t* __restrict__ W1T,
                       bf16_t* __restrict__ W2T, bf16_t* __restrict__ W3T,
                       float4* __restrict__ zero4) {
  int idx = blockIdx.x * blockDim.x + threadIdx.x;
  if (idx < 196608) {
    int n = idx / 768, k = idx - n * 768;
    W1T[idx] = (bf16_t)W1[k * 256 + n];
  } else if (idx < 196608 + 16384) {
    int i = idx - 196608;
    int n = i / 256, k = i - n * 256;
    W2T[i] = (bf16_t)W2[k * 64 + n];
  } else if (idx < 196608 + 16384 + 2048) {
    int i = idx - 196608 - 16384;
    int n = i / 64, k = i - n * 64;
    W3T[i] = (bf16_t)((n < 20) ? W3[k * 20 + n] : 0.0f);
  } else if (idx >= 215040) {
    int z = idx - 215040;  // 32768 float4 = 131072 f32 = sums+counts
    zero4[z] = (float4){0.f, 0.f, 0.f, 0.f};
  }
}

// ---- precompute: XL = l_embs @ W1_top ; XC = c_embs @ W1_bot + b1 (bf16 out) ----
// blocks [0, N_LITS/64) -> XL rows; [N_LITS/64, +N_CLAUSES/64) -> XC rows.
// 64 rows/block, 4 waves x 64 cols, K=384 in 4 chunks of 96.
// Epilogue: fragment -> LDS transpose -> coalesced bf16x8 stores.
__global__ __launch_bounds__(256, 3) void k_pre(
    const float* __restrict__ l_embs, const float* __restrict__ c_embs,
    const bf16_t* __restrict__ W1T, const float* __restrict__ b1,
    bf16_t* __restrict__ XLb, bf16_t* __restrict__ XCb)
{
  __shared__ __align__(16) bf16_t smem2[64 * XSTR];  // staging (ASTR view) U epilogue
  bf16_t* Abuf = smem2;

  const int t    = threadIdx.x;
  const int wave = t >> 6;
  const int lane = t & 63;
  const int m    = lane & 15;
  const int quad = lane >> 4;
  const int bid  = blockIdx.x;
  const bool isC = bid >= (N_LITS / 64);
  const int r0   = (isC ? bid - N_LITS / 64 : bid) * 64;
  const float* A = isC ? c_embs : l_embs;
  const int koff = isC ? FEAT : 0;   // which half of W1T's K range
  const int wn   = wave * 64;

  const int sr  = t >> 2;
  const int sub = t & 3;
  const float* pA = A + (size_t)(r0 + sr) * FEAT + sub * 4;
  bf16_t* sdst = Abuf + sr * ASTR + sub * 4;

  f32x4 acc[4][4];
#pragma unroll
  for (int mt = 0; mt < 4; ++mt)
#pragma unroll
    for (int nt = 0; nt < 4; ++nt) acc[mt][nt] = (f32x4){0.f, 0.f, 0.f, 0.f};

  const bf16_t* wb1 = W1T + (size_t)(wn + m) * F2 + koff + quad * 8;

  // prologue: stage chunk 0
  {
    float4 v[6];
#pragma unroll
    for (int q = 0; q < 6; ++q) v[q] = *(const float4*)(pA + q * 16);
#pragma unroll
    for (int q = 0; q < 6; ++q) {
      bf16x4 c;
      c[0] = (bf16_t)v[q].x; c[1] = (bf16_t)v[q].y;
      c[2] = (bf16_t)v[q].z; c[3] = (bf16_t)v[q].w;
      *(bf16x4*)(sdst + q * 16) = c;
    }
  }

  for (int cc = 0; cc < 4; ++cc) {
    float4 vn[6];
    if (cc < 3) {
#pragma unroll
      for (int q = 0; q < 6; ++q) vn[q] = *(const float4*)(pA + (cc + 1) * 96 + q * 16);
    }
    __syncthreads();
#pragma unroll
    for (int s = 0; s < 3; ++s) {
      bf16x8 af[4];
#pragma unroll
      for (int mt = 0; mt < 4; ++mt)
        af[mt] = *(const bf16x8*)(Abuf + (mt * 16 + m) * ASTR + s * 32 + quad * 8);
      const bf16_t* wb = wb1 + cc * 96 + s * 32;
#pragma unroll
      for (int nt = 0; nt < 4; ++nt) {
        bf16x8 b = *(const bf16x8*)(wb + (size_t)nt * 16 * F2);
#pragma unroll
        for (int mt = 0; mt < 4; ++mt)
          acc[mt][nt] = __builtin_amdgcn_mfma_f32_16x16x32_bf16(af[mt], b, acc[mt][nt], 0, 0, 0);
      }
    }
    if (cc < 3) {
      __syncthreads();
#pragma unroll
      for (int q = 0; q < 6; ++q) {
        bf16x4 c;
        c[0] = (bf16_t)vn[q].x; c[1] = (bf16_t)vn[q].y;
        c[2] = (bf16_t)vn[q].z; c[3] = (bf16_t)vn[q].w;
        *(bf16x4*)(sdst + q * 16) = c;
      }
    }
  }

  // ---- epilogue: fragments -> LDS (b1 folded into XC; no relu here) ----
  __syncthreads();   // all Abuf reads done before overwrite
#pragma unroll
  for (int nt = 0; nt < 4; ++nt) {
    int col = wn + nt * 16 + m;
    float badd = isC ? b1[col] : 0.0f;
#pragma unroll
    for (int mt = 0; mt < 4; ++mt)
#pragma unroll
      for (int r = 0; r < 4; ++r)
        smem2[(mt * 16 + quad * 4 + r) * XSTR + col] = (bf16_t)(acc[mt][nt][r] + badd);
  }
  __syncthreads();

  // coalesced store: 64 rows x 32 16B-chunks = 2048 chunks; 256 threads x 8
  bf16_t* X = isC ? XCb : XLb;
#pragma unroll
  for (int k = 0; k < 8; ++k) {
    int c    = t + k * 256;
    int row  = c >> 5;           // 32 chunks per row -> row in [0,64)
    int coff = (c & 31) * 8;     // element offset in row
    bf16x8 v = *(const bf16x8*)(smem2 + row * XSTR + coff);
    *(bf16x8*)(X + (size_t)(r0 + row) * H1 + coff) = v;
  }
}

// ---- per-edge: h1 = relu(XL[i] + XC[j]) in-register, layers 2-4, atomics ----
// 64 edges/block, 4 waves x 16 edges, no barriers.
__global__ __launch_bounds__(256, 8) void k_edge2(
    const bf16_t* __restrict__ XLb, const bf16_t* __restrict__ XCb,
    const int* __restrict__ edge_i, const int* __restrict__ edge_j,
    const bf16_t* __restrict__ W2T, const bf16_t* __restrict__ W3T,
    const float* __restrict__ b2, const float* __restrict__ b3,
    const float* __restrict__ W4, const float* __restrict__ b4,
    float* __restrict__ sc)
{
  __shared__ __align__(16) bf16_t h2s[64 * H2STR];

  const int t    = threadIdx.x;
  const int wave = t >> 6;
  const int lane = t & 63;
  const int m    = lane & 15;
  const int quad = lane >> 4;
  const int e0   = blockIdx.x * 64;
  const int er   = wave * 16;

  // this lane's A-fragment row = edge er+m
  const int e  = e0 + er + m;
  const int ri = edge_i[e];
  const int rj = edge_j[e];
  const size_t baseL = (size_t)ri * H1;
  const size_t baseC = (size_t)rj * H1;

  f32x4 acc2[4];
#pragma unroll
  for (int nt = 0; nt < 4; ++nt) acc2[nt] = (f32x4){0.f, 0.f, 0.f, 0.f};

  // layer 2: K=256 in 8 steps of 32; A built in-register from gathered rows
#pragma unroll
  for (int g = 0; g < 2; ++g) {
    bf16x8 xa[4], ya[4];
#pragma unroll
    for (int u = 0; u < 4; ++u) {
      const int off = (g * 4 + u) * 32 + quad * 8;
      xa[u] = *(const bf16x8*)(XLb + baseL + off);
      ya[u] = *(const bf16x8*)(XCb + baseC + off);
    }
    bf16x8 a2[4];
#pragma unroll
    for (int u = 0; u < 4; ++u) {
#pragma unroll
      for (int jj = 0; jj < 8; ++jj)
        a2[u][jj] = (bf16_t)fmaxf((float)xa[u][jj] + (float)ya[u][jj], 0.f);
    }
#pragma unroll
    for (int u = 0; u < 4; ++u) {
      const int s2 = g * 4 + u;
#pragma unroll
      for (int nt = 0; nt < 4; ++nt) {
        bf16x8 b = *(const bf16x8*)(W2T + (size_t)(nt * 16 + m) * H1 + s2 * 32 + quad * 8);
        acc2[nt] = __builtin_amdgcn_mfma_f32_16x16x32_bf16(a2[u], b, acc2[nt], 0, 0, 0);
      }
    }
  }

  // h2 -> LDS (rows er..er+15 owned by this wave; no barrier needed)
#pragma unroll
  for (int nt = 0; nt < 4; ++nt) {
    float bb = b2[nt * 16 + m];
#pragma unroll
    for (int r = 0; r < 4; ++r)
      h2s[(er + quad * 4 + r) * H2STR + nt * 16 + m] =
          (bf16_t)fmaxf(acc2[nt][r] + bb, 0.0f);
  }

  // layer 3: C3[16,32] = h2[16,64] @ W3pad
  f32x4 acc3[2];
#pragma unroll
  for (int nt = 0; nt < 2; ++nt) acc3[nt] = (f32x4){0.f, 0.f, 0.f, 0.f};
#pragma unroll
  for (int s3 = 0; s3 < 2; ++s3) {
    bf16x8 a3 = *(const bf16x8*)(h2s + (er + m) * H2STR + s3 * 32 + quad * 8);
#pragma unroll
    for (int nt = 0; nt < 2; ++nt) {
      bf16x8 b = *(const bf16x8*)(W3T + (size_t)(nt * 16 + m) * H2 + s3 * 32 + quad * 8);
      acc3[nt] = __builtin_amdgcn_mfma_f32_16x16x32_bf16(a3, b, acc3[nt], 0, 0, 0);
    }
  }

  // layer 4 + per-clause atomics (interleaved {sum,count})
  float b3A = b3[m];
  float b3B = (m + 16 < 20) ? b3[m + 16] : 0.0f;
  float w4A = W4[m];
  float w4B = (m + 16 < 20) ? W4[m + 16] : 0.0f;

  float p[4];
#pragma unroll
  for (int r = 0; r < 4; ++r) {
    float hA = fmaxf(acc3[0][r] + b3A, 0.0f);
    float hB = fmaxf(acc3[1][r] + b3B, 0.0f);
    p[r] = hA * w4A + hB * w4B;
  }
#pragma unroll
  for (int d = 1; d < 16; d <<= 1) {
#pragma unroll
    for (int r = 0; r < 4; ++r) p[r] += __shfl_xor(p[r], d, 64);
  }

  if (m == 0) {
    float bb4 = b4[0];
#pragma unroll
    for (int r = 0; r < 4; ++r) {
      int row = er + quad * 4 + r;
      int ej = edge_j[e0 + row];
      atomicAdd(&sc[2 * ej], p[r] + bb4);
      atomicAdd(&sc[2 * ej + 1], 1.0f);
    }
  }
}

// out[e] = sc[ej].sum / max(sc[ej].count, 1) — one 8B gather per edge
__global__ void k_gather(const float2* __restrict__ sc,
                         const int* __restrict__ edge_j, float* __restrict__ out) {
  int e = blockIdx.x * blockDim.x + threadIdx.x;
  if (e >= N_EDGES) return;
  float2 v = sc[edge_j[e]];
  out[e] = v.x / fmaxf(v.y, 1.0f);
}

extern "C" void kernel_launch(void* const* d_in, const int* in_sizes, int n_in,
                              void* d_out, int out_size, void* d_ws, size_t ws_size,
                              hipStream_t stream) {
  const float* l_embs = (const float*)d_in[0];
  const float* c_embs = (const float*)d_in[1];
  const int*   edge_i = (const int*)d_in[2];
  const int*   edge_j = (const int*)d_in[3];
  const float* W1 = (const float*)d_in[4];
  const float* b1 = (const float*)d_in[5];
  const float* W2 = (const float*)d_in[6];
  const float* b2 = (const float*)d_in[7];
  const float* W3 = (const float*)d_in[8];
  const float* b3 = (const float*)d_in[9];
  const float* W4 = (const float*)d_in[10];
  const float* b4 = (const float*)d_in[11];
  float* out = (float*)d_out;

  char* ws = (char*)d_ws;
  bf16_t* W1T = (bf16_t*)(ws + OFF_W1T);
  bf16_t* W2T = (bf16_t*)(ws + OFF_W2T);
  bf16_t* W3T = (bf16_t*)(ws + OFF_W3T);
  float*  sc  = (float*)(ws + OFF_SC);
  bf16_t* XLb = (bf16_t*)(ws + OFF_X);
  bf16_t* XCb = (bf16_t*)(ws + OFF_X + XL_BYTES);

  // weights transpose + sc zeroing fused (968 blocks x 256 covers both ranges)
  k_prep<<<968, 256, 0, stream>>>(W1, W2, W3, W1T, W2T, W3T, (float4*)sc);

  const int pre_grid = N_LITS / 64 + N_CLAUSES / 64;  // 3072
  k_pre<<<pre_grid, 256, 0, stream>>>(l_embs, c_embs, W1T, b1, XLb, XCb);

  k_edge2<<<N_EDGES / 64, 256, 0, stream>>>(
      XLb, XCb, edge_i, edge_j, W2T, W3T, b2, b3, W4, b4, sc);

  k_gather<<<N_EDGES / 256, 256, 0, stream>>>((const float2*)sc, edge_j, out);
}